// Round 2
// baseline (11734.816 us; speedup 1.0000x reference)
//
#include <hip/hip_runtime.h>
#include <math.h>

#define N_NODES 20000
#define D_INN   512
#define DH      256
#define NCH     7
#define NE      320000
#define NE2     100000
#define NB      8192
#define H3      2304   // 512 + 7*256
#define MAXN    0.996f

__device__ __forceinline__ float artanh_f(float x) {
    x = fminf(fmaxf(x, -1.0f + 1e-7f), 1.0f - 1e-7f);
    return 0.5f * (log1pf(x) - log1pf(-x));
}

// block of 256 threads -> sum over all threads, broadcast to all
__device__ __forceinline__ float block_sum256(float v) {
    __shared__ float sred[4];
    #pragma unroll
    for (int off = 32; off > 0; off >>= 1) v += __shfl_down(v, off, 64);
    int lane = threadIdx.x & 63;
    int w = threadIdx.x >> 6;
    if (lane == 0) sred[w] = v;
    __syncthreads();
    float tot = sred[0] + sred[1] + sred[2] + sred[3];
    __syncthreads();
    return tot;
}

__global__ void k_zero(float* __restrict__ p, int n) {
    int i = blockIdx.x * 256 + threadIdx.x;
    if (i < n) p[i] = 0.0f;
}

// x_hyp = proj(expmap0(f1)); store projected row norm (clamped) in xhn
__global__ void k_expmap_proj_in(const float* __restrict__ f1,
                                 float* __restrict__ xhyp, float* __restrict__ xhn) {
    int r = blockIdx.x, t = threadIdx.x;
    const float* u = f1 + (size_t)r * D_INN;
    float v0 = u[t], v1 = u[t + 256];
    float ss = block_sum256(v0 * v0 + v1 * v1);
    float nraw = sqrtf(ss);
    float n = fmaxf(nraw, 1e-15f);
    float c = tanhf(n) / n;
    float ny = c * nraw;                 // norm of expmap0 output
    float np = fmaxf(ny, 1e-15f);
    float s = (np > MAXN) ? MAXN / np : 1.0f;
    float cs = c * s;
    float* o = xhyp + (size_t)r * D_INN;
    o[t] = cs * v0;
    o[t + 256] = cs * v1;
    if (t == 0) xhn[r] = fminf(np, MAXN);   // = max(||x_hyp||,1e-15)
}

// hb[i] = proj(expmap0(b_hyp[i])), hb2[i] = ||hb||^2
__global__ void k_hb(const float* __restrict__ b_hyp,
                     float* __restrict__ hb, float* __restrict__ hb2) {
    int i = blockIdx.x, t = threadIdx.x;
    float v = b_hyp[i * DH + t];
    float ss = block_sum256(v * v);
    float nraw = sqrtf(ss);
    float n = fmaxf(nraw, 1e-15f);
    float c = tanhf(n) / n;
    float ny = c * nraw;
    float np = fmaxf(ny, 1e-15f);
    float s = (np > MAXN) ? MAXN / np : 1.0f;
    float hv = c * s * v;
    hb[i * DH + t] = hv;
    float s2 = block_sum256(hv * hv);
    if (t == 0) hb2[i] = s2;
}

// in-place on T1 row (=mx): mobius_matvec finalize -> proj -> mobius_add(hb) -> proj -> logmap0
__global__ void k_rowfuse1(float* __restrict__ T1, const float* __restrict__ xhn,
                           const float* __restrict__ hb, const float* __restrict__ hb2) {
    int r = blockIdx.x, t = threadIdx.x;
    float* row = T1 + (size_t)r * DH;
    float m = row[t];
    float ss = block_sum256(m * m);
    float mxn_raw = sqrtf(ss);
    float mxn = fmaxf(mxn_raw, 1e-15f);
    float xn = xhn[r];
    float tt = tanhf(mxn / xn * artanh_f(xn));
    float coef = tt / mxn;
    float res = coef * m;
    float nres = coef * mxn_raw;
    // proj
    float np = fmaxf(nres, 1e-15f);
    float s1 = (np > MAXN) ? MAXN / np : 1.0f;
    res *= s1;
    float n1 = fminf(np, MAXN);
    // mobius_add(res, hb)
    float hbv = hb[t];
    float xy = block_sum256(res * hbv);
    float x2 = n1 * n1, y2 = hb2[0];
    float num = (1.0f + 2.0f * xy + y2) * res + (1.0f - x2) * hbv;
    float den = fmaxf(1.0f + 2.0f * xy + x2 * y2, 1e-15f);
    float o = num / den;
    // proj
    float no2 = block_sum256(o * o);
    float nop = fmaxf(sqrtf(no2), 1e-15f);
    float s2 = (nop > MAXN) ? MAXN / nop : 1.0f;
    float p = o * s2;
    float n2 = fminf(nop, MAXN);
    // logmap0
    row[t] = artanh_f(n2) / n2 * p;
}

// in-place on T2 row (=support): expmap0->proj->logmap0->relu->expmap0->proj->logmap0
__global__ void k_rowfuse2(float* __restrict__ T2) {
    int r = blockIdx.x, t = threadIdx.x;
    float* row = T2 + (size_t)r * DH;
    float sv = row[t];
    float ss = block_sum256(sv * sv);
    float nraw = sqrtf(ss);
    float n = fmaxf(nraw, 1e-15f);
    float c1 = tanhf(n) / n;
    float h = c1 * sv;
    float nh = c1 * nraw;
    float np1 = fmaxf(nh, 1e-15f);
    float s1 = (np1 > MAXN) ? MAXN / np1 : 1.0f;
    h *= s1;
    float n1 = fminf(np1, MAXN);
    float u = artanh_f(n1) / n1 * h;
    u = fmaxf(u, 0.0f);                       // relu in tangent space
    float ss2 = block_sum256(u * u);
    float n2raw = sqrtf(ss2);
    float n2 = fmaxf(n2raw, 1e-15f);
    float c3 = tanhf(n2) / n2;
    float e = c3 * u;
    float ne = c3 * n2raw;
    float np3 = fmaxf(ne, 1e-15f);
    float s3 = (np3 > MAXN) ? MAXN / np3 : 1.0f;
    e *= s3;
    float n3 = fminf(np3, MAXN);
    row[t] = artanh_f(n3) / n3 * e;
}

__global__ void k_scatter_scale(const int* __restrict__ src, const int* __restrict__ dst,
                                const float* __restrict__ val, const float* __restrict__ xt,
                                float* __restrict__ sup) {
    int e = blockIdx.x;
    int s = src[e], d = dst[e];
    float v = val[e];
    int j = threadIdx.x;
    atomicAdd(&sup[(size_t)d * DH + j], v * xt[(size_t)s * DH + j]);
}

__global__ void k_scatter_add(const int* __restrict__ src, const int* __restrict__ dst,
                              const float* __restrict__ dv, float* __restrict__ agg) {
    int e = blockIdx.x;
    int s = src[e], d = dst[e];
    int j = threadIdx.x;
    atomicAdd(&agg[(size_t)d * DH + j], dv[(size_t)s * DH + j]);
}

__global__ void k_colstats(const float* __restrict__ z,
                           float* __restrict__ csum, float* __restrict__ csq) {
    int t = threadIdx.x;
    int r0 = blockIdx.x * 100;
    float s = 0.0f, q = 0.0f;
    for (int r = r0; r < r0 + 100; ++r) {
        float v = z[(size_t)r * DH + t];
        s += v;
        q += v * v;
    }
    atomicAdd(&csum[t], s);
    atomicAdd(&csq[t], q);
}

__global__ void k_normtanh(float* __restrict__ z, const float* __restrict__ csum,
                           const float* __restrict__ csq, const float* __restrict__ gamma,
                           const float* __restrict__ beta) {
    int idx = blockIdx.x * 256 + threadIdx.x;
    int j = idx & 255;
    float mu = csum[j] * (1.0f / N_NODES);
    float var = csq[j] * (1.0f / N_NODES) - mu * mu;
    float inv = 1.0f / sqrtf(var + 1e-5f);
    float v = (z[idx] - mu) * inv * gamma[j] + beta[j];
    z[idx] = tanhf(v);
}

// f1 slice of S,P (cols 0..511), done once
__global__ void k_pair0(const int* __restrict__ ei, const int* __restrict__ eid,
                        const float* __restrict__ f1, float* __restrict__ S,
                        float* __restrict__ P) {
    int b = blockIdx.x, t = threadIdx.x;
    int e = eid[b];
    int n0 = ei[e], n1 = ei[NE2 + e];
    const float* xa = f1 + (size_t)n0 * D_INN;
    const float* xb = f1 + (size_t)n1 * D_INN;
    float* so = S + (size_t)b * H3;
    float* po = P + (size_t)b * H3;
    for (int j = t; j < D_INN; j += 256) {
        float a = xa[j], c = xb[j];
        so[j] = a + c;
        po[j] = a * c;
    }
}

// channel slice of S,P (256 cols at col0) gathered from z (20000x256)
__global__ void k_gather_ch(const int* __restrict__ ei, const int* __restrict__ eid,
                            const float* __restrict__ z, float* __restrict__ S,
                            float* __restrict__ P, int col0) {
    int b = blockIdx.x, j = threadIdx.x;
    int e = eid[b];
    int n0 = ei[e], n1 = ei[NE2 + e];
    float a = z[(size_t)n0 * DH + j];
    float c = z[(size_t)n1 * DH + j];
    S[(size_t)b * H3 + col0 + j] = a + c;
    P[(size_t)b * H3 + col0 + j] = a * c;
}

__global__ void k_final(const float* __restrict__ h2, const float* __restrict__ Wf3,
                        const float* __restrict__ bf3, float* __restrict__ out) {
    int r = blockIdx.x, t = threadIdx.x;
    const float* hr = h2 + (size_t)r * 576;
    float acc[7] = {0, 0, 0, 0, 0, 0, 0};
    for (int cb = t; cb < 576; cb += 64) {
        float h = hr[cb];
        #pragma unroll
        for (int o = 0; o < 7; ++o) acc[o] = fmaf(h, Wf3[o * 576 + cb], acc[o]);
    }
    #pragma unroll
    for (int o = 0; o < 7; ++o) {
        #pragma unroll
        for (int off = 32; off > 0; off >>= 1) acc[o] += __shfl_down(acc[o], off, 64);
    }
    if (t == 0) {
        #pragma unroll
        for (int o = 0; o < 7; ++o) out[(size_t)r * 7 + o] = acc[o] + bf3[o];
    }
}

// ----- fp32 GEMM: out[M,Nc] = A[M,K] @ W[Nc,K]^T + bias, row-major, K%16==0, Nc%64==0.
// EP: 0=none, 1=dual-store(out+out2), 2=sigmoid, 3=relu, 4=aux*relu
template <int EP>
__global__ __launch_bounds__(256, 2) void k_gemm(const float* __restrict__ A,
                                                 const float* __restrict__ W,
                                                 const float* __restrict__ bias,
                                                 float* __restrict__ out, int M, int K, int ldo,
                                                 const float* __restrict__ aux,
                                                 float* __restrict__ out2, int ldaux) {
    __shared__ float As[16][68];
    __shared__ float Ws[16][68];
    const int t = threadIdx.x;
    const int tx = t & 15, ty = t >> 4;
    const int row0 = blockIdx.y * 64, col0 = blockIdx.x * 64;
    const int lr = t >> 2, lk = (t & 3) << 2;
    float acc[4][4] = {};
    int ar = row0 + lr;
    if (ar >= M) ar = M - 1;
    const float* Aptr = A + (size_t)ar * K + lk;
    const float* Wptr = W + (size_t)(col0 + lr) * K + lk;
    for (int k0 = 0; k0 < K; k0 += 16) {
        float4 av = *reinterpret_cast<const float4*>(Aptr + k0);
        float4 wv = *reinterpret_cast<const float4*>(Wptr + k0);
        As[lk + 0][lr] = av.x; As[lk + 1][lr] = av.y; As[lk + 2][lr] = av.z; As[lk + 3][lr] = av.w;
        Ws[lk + 0][lr] = wv.x; Ws[lk + 1][lr] = wv.y; Ws[lk + 2][lr] = wv.z; Ws[lk + 3][lr] = wv.w;
        __syncthreads();
        #pragma unroll
        for (int k = 0; k < 16; ++k) {
            float4 a4 = *reinterpret_cast<const float4*>(&As[k][ty << 2]);
            float4 b4 = *reinterpret_cast<const float4*>(&Ws[k][tx << 2]);
            float avv[4] = {a4.x, a4.y, a4.z, a4.w};
            float bvv[4] = {b4.x, b4.y, b4.z, b4.w};
            #pragma unroll
            for (int i = 0; i < 4; ++i)
                #pragma unroll
                for (int j = 0; j < 4; ++j) acc[i][j] = fmaf(avv[i], bvv[j], acc[i][j]);
        }
        __syncthreads();
    }
    #pragma unroll
    for (int i = 0; i < 4; ++i) {
        int r = row0 + (ty << 2) + i;
        if (r >= M) continue;
        #pragma unroll
        for (int j = 0; j < 4; ++j) {
            int cc = col0 + (tx << 2) + j;
            float v = acc[i][j] + (bias ? bias[cc] : 0.0f);
            if (EP == 2) v = 1.0f / (1.0f + expf(-v));
            if (EP == 3) v = fmaxf(v, 0.0f);
            if (EP == 4) v = aux[(size_t)r * ldaux + cc] * fmaxf(v, 0.0f);
            out[(size_t)r * ldo + cc] = v;
            if (EP == 1) out2[(size_t)r * ldo + cc] = v;
        }
    }
}

static inline void gemm_run(int ep, const float* A, const float* W, const float* bias, float* out,
                            int M, int Nc, int K, int ldo, const float* aux, float* out2,
                            int ldaux, hipStream_t st) {
    dim3 g(Nc / 64, (M + 63) / 64);
    switch (ep) {
        case 0: k_gemm<0><<<g, 256, 0, st>>>(A, W, bias, out, M, K, ldo, aux, out2, ldaux); break;
        case 1: k_gemm<1><<<g, 256, 0, st>>>(A, W, bias, out, M, K, ldo, aux, out2, ldaux); break;
        case 2: k_gemm<2><<<g, 256, 0, st>>>(A, W, bias, out, M, K, ldo, aux, out2, ldaux); break;
        case 3: k_gemm<3><<<g, 256, 0, st>>>(A, W, bias, out, M, K, ldo, aux, out2, ldaux); break;
        case 4: k_gemm<4><<<g, 256, 0, st>>>(A, W, bias, out, M, K, ldo, aux, out2, ldaux); break;
    }
}

extern "C" void kernel_launch(void* const* d_in, const int* in_sizes, int n_in, void* d_out,
                              int out_size, void* d_ws, size_t ws_size, hipStream_t stream) {
    const float* f1 = (const float*)d_in[0];
    const int* adj_src = (const int*)d_in[1];
    const int* adj_dst = (const int*)d_in[2];
    const float* adj_val = (const float*)d_in[3];
    const int* edge_src = (const int*)d_in[4];
    const int* edge_dst = (const int*)d_in[5];
    const int* edge_index = (const int*)d_in[6];
    const int* edge_id = (const int*)d_in[7];
    const float* W_hyp = (const float*)d_in[8];
    const float* b_hyp = (const float*)d_in[9];
    const float* Wd = (const float*)d_in[10];
    const float* bd = (const float*)d_in[11];
    const float* Wg1 = (const float*)d_in[12];
    const float* bg1 = (const float*)d_in[13];
    const float* gamma = (const float*)d_in[14];
    const float* beta = (const float*)d_in[15];
    const float* Wg2 = (const float*)d_in[16];
    const float* bg2 = (const float*)d_in[17];
    const float* Wgate = (const float*)d_in[18];
    const float* bgate = (const float*)d_in[19];
    const float* Wint = (const float*)d_in[20];
    const float* bint = (const float*)d_in[21];
    const float* Wout = (const float*)d_in[22];
    const float* bout = (const float*)d_in[23];
    const float* Wf1 = (const float*)d_in[24];
    const float* bf1 = (const float*)d_in[25];
    const float* Wf2 = (const float*)d_in[26];
    const float* bf2 = (const float*)d_in[27];
    const float* Wf3 = (const float*)d_in[28];
    const float* bf3 = (const float*)d_in[29];
    float* outp = (float*)d_out;

    // ---- workspace layout (253.5 MB peak) ----
    char* base = (char*)d_ws;
    const size_t SB = (size_t)NB * H3 * 4;           // 75,497,472 B
    float* S = (float*)base;                         // 8192x2304, persists
    float* P = (float*)(base + SB);                  // 8192x2304, persists
    float* pool = (float*)(base + 2 * SB);           // 102.4 MB shared pool
    // GNN-phase view of pool:
    float* xhyp = pool;                              // 20000x512
    float* T1 = pool + (size_t)N_NODES * D_INN;      // 20000x256
    float* T2 = T1 + (size_t)N_NODES * DH;
    float* T3 = T2 + (size_t)N_NODES * DH;
    // stage-C view of pool (GNN temps dead by then):
    const size_t CC = (size_t)2048 * H3;             // chunk cols
    float* Gc = pool;
    float* GIc = pool + CC;
    float* gc = pool + 2 * CC;
    float* h1c = pool + 3 * CC;                      // 2048x1152
    float* h2c = h1c + (size_t)2048 * 1152;          // 2048x576
    // small stats after pool:
    float* sm = pool + (size_t)N_NODES * D_INN + 3 * (size_t)N_NODES * DH;
    float* xhn = sm;                 // 20000
    float* hb = xhn + N_NODES;       // 7*256
    float* hb2 = hb + NCH * DH;      // 7
    float* csum = hb2 + NCH + 2;     // 256 (+2 pad keeps 8B align irrelevant for floats)
    float* csq = csum + DH;          // 256

    k_expmap_proj_in<<<N_NODES, 256, 0, stream>>>(f1, xhyp, xhn);
    k_hb<<<NCH, 256, 0, stream>>>(b_hyp, hb, hb2);
    k_pair0<<<NB, 256, 0, stream>>>(edge_index, edge_id, f1, S, P);

    for (int ch = 0; ch < NCH; ++ch) {
        // mx = x_hyp @ W_hyp[ch].T
        gemm_run(0, xhyp, W_hyp + (size_t)ch * DH * D_INN, nullptr, T1, N_NODES, DH, D_INN, DH,
                 nullptr, nullptr, 0, stream);
        k_rowfuse1<<<N_NODES, 256, 0, stream>>>(T1, xhn, hb + ch * DH, hb2 + ch);
        k_zero<<<(N_NODES * DH) / 256, 256, 0, stream>>>(T2, N_NODES * DH);
        k_scatter_scale<<<NE, 256, 0, stream>>>(adj_src + (size_t)ch * NE,
                                                adj_dst + (size_t)ch * NE,
                                                adj_val + (size_t)ch * NE, T1, T2);
        k_rowfuse2<<<N_NODES, 256, 0, stream>>>(T2);
        // d = u @ Wd.T + bd  (store to T1 and T3; T3 becomes agg's init)
        gemm_run(1, T2, Wd + (size_t)ch * DH * DH, bd + ch * DH, T1, N_NODES, DH, DH, DH, nullptr,
                 T3, 0, stream);
        k_scatter_add<<<NE, 256, 0, stream>>>(edge_src + (size_t)ch * NE,
                                              edge_dst + (size_t)ch * NE, T1, T3);
        // z = agg @ Wg1.T + bg1
        gemm_run(0, T3, Wg1 + (size_t)ch * DH * DH, bg1 + ch * DH, T1, N_NODES, DH, DH, DH,
                 nullptr, nullptr, 0, stream);
        k_zero<<<2, 256, 0, stream>>>(csum, 2 * DH);
        k_colstats<<<200, 256, 0, stream>>>(T1, csum, csq);
        k_normtanh<<<N_NODES, 256, 0, stream>>>(T1, csum, csq, gamma + ch * DH, beta + ch * DH);
        // z_ch = zt @ Wg2.T + bg2 -> T2, then gather into S,P columns
        gemm_run(0, T1, Wg2 + (size_t)ch * DH * DH, bg2 + ch * DH, T2, N_NODES, DH, DH, DH,
                 nullptr, nullptr, 0, stream);
        k_gather_ch<<<NB, 256, 0, stream>>>(edge_index, edge_id, T2, S, P, D_INN + ch * DH);
    }

    // stage C: edge-pair MLP, chunked over B to fit the pool
    for (int cb = 0; cb < NB; cb += 2048) {
        const float* Sc = S + (size_t)cb * H3;
        const float* Pc = P + (size_t)cb * H3;
        gemm_run(2, Sc, Wgate, bgate, Gc, 2048, H3, H3, H3, nullptr, nullptr, 0, stream);
        gemm_run(4, Pc, Wint, bint, GIc, 2048, H3, H3, H3, Gc, nullptr, H3, stream);
        gemm_run(0, GIc, Wout, bout, gc, 2048, H3, H3, H3, nullptr, nullptr, 0, stream);
        gemm_run(3, gc, Wf1, bf1, h1c, 2048, 1152, H3, 1152, nullptr, nullptr, 0, stream);
        gemm_run(3, h1c, Wf2, bf2, h2c, 2048, 576, 1152, 576, nullptr, nullptr, 0, stream);
        k_final<<<2048, 64, 0, stream>>>(h2c, Wf3, bf3, outp + (size_t)cb * 7);
    }
}